// Round 10
// baseline (5081.483 us; speedup 1.0000x reference)
//
#include <hip/hip_runtime.h>
#include <hip/hip_bf16.h>
#include <math.h>

#define MINN 1e-7f

// Problem dims (fixed by setup_inputs)
#define BB 64
#define SS 128
#define NCOL 3840            // 768 (W_d) + 4*768 (gates)

typedef float f4 __attribute__((ext_vector_type(4)));
typedef short bf16x8 __attribute__((ext_vector_type(8)));
typedef float f32x4 __attribute__((ext_vector_type(4)));

__device__ __forceinline__ float artanh_c(float x) {
  x = fminf(fmaxf(x, -1.0f + 1e-6f), 1.0f - 1e-6f);
  return atanhf(x);
}
__device__ __forceinline__ float tan_k_(float x, float sq) { return tanhf(sq * x) / sq; }
__device__ __forceinline__ float artan_k_(float x, float sq) { return artanh_c(sq * x) / sq; }

// Block reduction over 256 threads (4 waves).
template <int N>
__device__ __forceinline__ void block_reduce_sum(float* v, float* red) {
#pragma unroll
  for (int m = 1; m < 64; m <<= 1) {
#pragma unroll
    for (int i = 0; i < N; ++i) v[i] += __shfl_xor(v[i], m, 64);
  }
  int wid = threadIdx.x >> 6;
  int lane = threadIdx.x & 63;
  if (lane == 0) {
#pragma unroll
    for (int i = 0; i < N; ++i) red[wid * N + i] = v[i];
  }
  __syncthreads();
#pragma unroll
  for (int i = 0; i < N; ++i) v[i] = red[i] + red[N + i] + red[2 * N + i] + red[3 * N + i];
  __syncthreads();
}

// Build combined weight matrix as bf16 hi/lo, [col][k] (k-contiguous = B-fragment ready).
__global__ __launch_bounds__(256) void k_build_cw(const float* __restrict__ W_all,
                                                  const float* __restrict__ W_d,
                                                  __hip_bfloat16* __restrict__ CWh,
                                                  __hip_bfloat16* __restrict__ CWl) {
  int col = blockIdx.x;  // 0..3839
#pragma unroll
  for (int p = 0; p < 3; ++p) {
    int k = threadIdx.x + 256 * p;
    float v;
    if (col < 768) {
      v = W_d[col * 768 + k];
    } else {
      int jm = col - 768;
      int g = jm / 768;
      int j2 = jm - g * 768;
      v = W_all[j2 * 3072 + g * 768 + k];
    }
    __hip_bfloat16 h = __float2bfloat16(v);
    CWh[(size_t)col * 768 + k] = h;
    CWl[(size_t)col * 768 + k] = __float2bfloat16(v - __bfloat162float(h));
  }
}

// Init: fp32 row-major state + bf16 hi/lo row-major copies (A-fragment ready).
__global__ __launch_bounds__(256) void k_init_state(
    const float* __restrict__ h0, const float* __restrict__ c0,
    float* __restrict__ ccR, float* __restrict__ hR,
    __hip_bfloat16* __restrict__ CH, __hip_bfloat16* __restrict__ CL,
    __hip_bfloat16* __restrict__ HH, __hip_bfloat16* __restrict__ HL) {
  int r = blockIdx.x;
#pragma unroll
  for (int p = 0; p < 3; ++p) {
    int j = threadIdx.x + 256 * p;
    float cv = c0[r * 768 + j];
    float hv = h0[r * 768 + j];
    ccR[r * 768 + j] = cv;
    hR[r * 768 + j] = hv;
    __hip_bfloat16 ch = __float2bfloat16(cv);
    CH[r * 768 + j] = ch;
    CL[r * 768 + j] = __float2bfloat16(cv - __bfloat162float(ch));
    __hip_bfloat16 hh = __float2bfloat16(hv);
    HH[r * 768 + j] = hh;
    HL[r * 768 + j] = __float2bfloat16(hv - __bfloat162float(hh));
  }
}

__global__ __launch_bounds__(256) void k_xnorm(const float* __restrict__ X,
                                               float* __restrict__ XN) {
  __shared__ float red[4];
  int r = blockIdx.x;
  float s = 0.f;
#pragma unroll
  for (int p = 0; p < 3; ++p) {
    float v = X[(size_t)r * 768 + threadIdx.x + 256 * p];
    s += v * v;
  }
#pragma unroll
  for (int m = 1; m < 64; m <<= 1) s += __shfl_xor(s, m, 64);
  if ((threadIdx.x & 63) == 0) red[threadIdx.x >> 6] = s;
  __syncthreads();
  if (threadIdx.x == 0) XN[r] = fmaxf(sqrtf(red[0] + red[1] + red[2] + red[3]), MINN);
}

// Split fp32 -> bf16 hi + bf16 lo (residual). Processes 4 elems/thread.
__global__ __launch_bounds__(256) void k_split(const float* __restrict__ src,
                                               __hip_bfloat16* __restrict__ hi,
                                               __hip_bfloat16* __restrict__ lo, int n4) {
  int i = blockIdx.x * 256 + threadIdx.x;
  if (i >= n4) return;
  f4 v = *(const f4*)(src + (size_t)i * 4);
#pragma unroll
  for (int j = 0; j < 4; ++j) {
    float x = (j == 0) ? v.x : (j == 1) ? v.y : (j == 2) ? v.z : v.w;
    __hip_bfloat16 h = __float2bfloat16(x);
    float r = x - __bfloat162float(h);
    hi[(size_t)i * 4 + j] = h;
    lo[(size_t)i * 4 + j] = __float2bfloat16(r);
  }
}

// MFMA U-path GEMM (r8-proven): OUT[i][m] = sum_k X[i][k]*U[m][k].
__global__ __launch_bounds__(256) void k_gemm_xu_mfma(
    const __hip_bfloat16* __restrict__ Xh, const __hip_bfloat16* __restrict__ Xl,
    const __hip_bfloat16* __restrict__ Uh, const __hip_bfloat16* __restrict__ Ul,
    __hip_bfloat16* __restrict__ OUT) {
  int tid = threadIdx.x;
  int wave = tid >> 6, lane = tid & 63;
  int r = lane & 15, kg = lane >> 4;
  int i0 = blockIdx.x * 64 + wave * 16;
  int m0 = blockIdx.y * 64;
  const __hip_bfloat16* xh = Xh + (size_t)(i0 + r) * 768 + kg * 8;
  const __hip_bfloat16* xl = Xl + (size_t)(i0 + r) * 768 + kg * 8;
  const __hip_bfloat16* uh = Uh + (size_t)(m0 + r) * 768 + kg * 8;
  const __hip_bfloat16* ul = Ul + (size_t)(m0 + r) * 768 + kg * 8;
  f32x4 acc0 = {0.f, 0.f, 0.f, 0.f};
  f32x4 acc1 = acc0, acc2 = acc0, acc3 = acc0;
  for (int k0 = 0; k0 < 768; k0 += 32) {
    bf16x8 ah = *(const bf16x8*)(xh + k0);
    bf16x8 al = *(const bf16x8*)(xl + k0);
    bf16x8 b0h = *(const bf16x8*)(uh + k0);
    bf16x8 b0l = *(const bf16x8*)(ul + k0);
    bf16x8 b1h = *(const bf16x8*)(uh + 12288 + k0);
    bf16x8 b1l = *(const bf16x8*)(ul + 12288 + k0);
    bf16x8 b2h = *(const bf16x8*)(uh + 24576 + k0);
    bf16x8 b2l = *(const bf16x8*)(ul + 24576 + k0);
    bf16x8 b3h = *(const bf16x8*)(uh + 36864 + k0);
    bf16x8 b3l = *(const bf16x8*)(ul + 36864 + k0);
    acc0 = __builtin_amdgcn_mfma_f32_16x16x32_bf16(ah, b0h, acc0, 0, 0, 0);
    acc1 = __builtin_amdgcn_mfma_f32_16x16x32_bf16(ah, b1h, acc1, 0, 0, 0);
    acc2 = __builtin_amdgcn_mfma_f32_16x16x32_bf16(ah, b2h, acc2, 0, 0, 0);
    acc3 = __builtin_amdgcn_mfma_f32_16x16x32_bf16(ah, b3h, acc3, 0, 0, 0);
    acc0 = __builtin_amdgcn_mfma_f32_16x16x32_bf16(al, b0h, acc0, 0, 0, 0);
    acc1 = __builtin_amdgcn_mfma_f32_16x16x32_bf16(al, b1h, acc1, 0, 0, 0);
    acc2 = __builtin_amdgcn_mfma_f32_16x16x32_bf16(al, b2h, acc2, 0, 0, 0);
    acc3 = __builtin_amdgcn_mfma_f32_16x16x32_bf16(al, b3h, acc3, 0, 0, 0);
    acc0 = __builtin_amdgcn_mfma_f32_16x16x32_bf16(ah, b0l, acc0, 0, 0, 0);
    acc1 = __builtin_amdgcn_mfma_f32_16x16x32_bf16(ah, b1l, acc1, 0, 0, 0);
    acc2 = __builtin_amdgcn_mfma_f32_16x16x32_bf16(ah, b2l, acc2, 0, 0, 0);
    acc3 = __builtin_amdgcn_mfma_f32_16x16x32_bf16(ah, b3l, acc3, 0, 0, 0);
  }
#pragma unroll
  for (int j = 0; j < 4; ++j) {
    size_t row = (size_t)(i0 + kg * 4 + j) * 3072 + m0 + r;
    OUT[row] = __float2bfloat16(acc0[j]);
    OUT[row + 16] = __float2bfloat16(acc1[j]);
    OUT[row + 32] = __float2bfloat16(acc2[j]);
    OUT[row + 48] = __float2bfloat16(acc3[j]);
  }
}

// Fused per-step kernel: GEMM (all 240 WGs) -> fence-free handoff -> pw (WGs 0..63).
// GOUT moves via volatile (sc0/sc1) write-through stores + volatile loads, so no
// cache fences are needed. State/weights stay on normal cached paths (cross-launch
// coherence handles them). Counter is monotonic; reset by graph memset node.
__global__ __launch_bounds__(256) void k_step(
    const __hip_bfloat16* __restrict__ CWh, const __hip_bfloat16* __restrict__ CWl,
    float* __restrict__ GOUT, unsigned int* __restrict__ cnt,
    const __hip_bfloat16* __restrict__ UG, const float* __restrict__ XN,
    const float* __restrict__ TS, const float* __restrict__ kptr,
    float* __restrict__ ccR, float* __restrict__ hR,
    __hip_bfloat16* __restrict__ CH, __hip_bfloat16* __restrict__ CL,
    __hip_bfloat16* __restrict__ HH, __hip_bfloat16* __restrict__ HL,
    float* __restrict__ out, int t) {
  __shared__ float red[64];
  int j = blockIdx.x;  // col-tile 0..239
  int tid = threadIdx.x;

  // ---------------- Phase G: MFMA GEMM (all 240 WGs) ----------------
  {
    int wave = tid >> 6, lane = tid & 63;
    int r = lane & 15, kg = lane >> 4;
    int i0 = wave * 16;
    int m0 = j * 16;
    const __hip_bfloat16* sh = (j < 48 ? CH : HH) + (size_t)(i0 + r) * 768 + kg * 8;
    const __hip_bfloat16* sl = (j < 48 ? CL : HL) + (size_t)(i0 + r) * 768 + kg * 8;
    const __hip_bfloat16* wh = CWh + (size_t)(m0 + r) * 768 + kg * 8;
    const __hip_bfloat16* wl = CWl + (size_t)(m0 + r) * 768 + kg * 8;
    f32x4 acc = {0.f, 0.f, 0.f, 0.f};
#pragma unroll 4
    for (int k0 = 0; k0 < 768; k0 += 32) {
      bf16x8 ah = *(const bf16x8*)(sh + k0);
      bf16x8 al = *(const bf16x8*)(sl + k0);
      bf16x8 bh = *(const bf16x8*)(wh + k0);
      bf16x8 bl = *(const bf16x8*)(wl + k0);
      acc = __builtin_amdgcn_mfma_f32_16x16x32_bf16(ah, bh, acc, 0, 0, 0);
      acc = __builtin_amdgcn_mfma_f32_16x16x32_bf16(al, bh, acc, 0, 0, 0);
      acc = __builtin_amdgcn_mfma_f32_16x16x32_bf16(ah, bl, acc, 0, 0, 0);
    }
#pragma unroll
    for (int jj = 0; jj < 4; ++jj)
      *(volatile float*)&GOUT[(size_t)(i0 + kg * 4 + jj) * NCOL + m0 + r] = acc[jj];
  }
  __syncthreads();  // drains vmcnt(0): all this WG's GOUT stores at coherence point
  if (tid == 0) atomicAdd(cnt, 1u);  // no-return device-scope add (fire & forget)
  if (j >= BB) return;

  // ---------------- Handoff: wait for all 240 producers ----------------
  unsigned int target = 240u * (unsigned int)(t + 1);
  if (tid == 0) {
    while (__hip_atomic_load(cnt, __ATOMIC_RELAXED, __HIP_MEMORY_SCOPE_AGENT) < target) {
      __builtin_amdgcn_s_sleep(4);
    }
  }
  __syncthreads();

  // ---------------- Phase P: pointwise hyperbolic update (WGs 0..63) ------
  int r = j;
  float kk = kptr[0];
  float sq = sqrtf(-kk);
  const float* grow = GOUT + r * NCOL;
  int i = r * SS + t;
  const __hip_bfloat16* urow = UG + (size_t)i * 3072;

  float cc[3], h[3], mv[3], gh[4][3], mx[4][3];
#pragma unroll
  for (int p = 0; p < 3; ++p) {
    int jj = tid + 256 * p;
    cc[p] = ccR[r * 768 + jj];
    h[p] = hR[r * 768 + jj];
    mv[p] = *(volatile const float*)&grow[jj];
#pragma unroll
    for (int g = 0; g < 4; ++g) {
      gh[g][p] = *(volatile const float*)&grow[768 + g * 768 + jj];
      mx[g][p] = __bfloat162float(urow[g * 768 + jj]);
    }
  }

  float sv[15];
#pragma unroll
  for (int q = 0; q < 15; ++q) sv[q] = 0.f;
#pragma unroll
  for (int p = 0; p < 3; ++p) {
    sv[0] += cc[p] * cc[p];
    sv[1] += h[p] * h[p];
    sv[2] += mv[p] * mv[p];
#pragma unroll
    for (int g = 0; g < 4; ++g) {
      sv[3 + g] += gh[g][p] * gh[g][p];
      sv[7 + g] += gh[g][p] * mx[g][p];
      sv[11 + g] += mx[g][p] * mx[g][p];
    }
  }
  block_reduce_sum<15>(sv, red);
  float c2 = sv[0], h2 = sv[1], mvn2 = sv[2];
  float xn_c = fmaxf(sqrtf(c2), MINN);
  float xn_h = fmaxf(sqrtf(h2), MINN);
  float mxn_d = fmaxf(sqrtf(mvn2), MINN);

  float r_d = (mxn_d / xn_c) * artan_k_(xn_c, sq);
  float twd = tan_k_(r_d, sq);
  float wdsc = twd / mxn_d;
  float yn_d = fmaxf(fabsf(twd), MINN);
  float lsc = (artan_k_(yn_d, sq) / yn_d) * wdsc;
  float th[3];
#pragma unroll
  for (int p = 0; p < 3; ++p) th[p] = tanhf(lsc * mv[p]);

  float uxn = XN[i];
  float ak_h = artan_k_(xn_h, sq);
  float ak_u = artan_k_(uxn, sq);
  float cAg[4], cBg[4], pscg[4];
#pragma unroll
  for (int g = 0; g < 4; ++g) {
    float ghn = fmaxf(sqrtf(sv[3 + g]), MINN);
    float tg = tan_k_((ghn / xn_h) * ak_h, sq);
    float wsc = tg / ghn;
    float w2 = tg * tg;
    float umxn = fmaxf(sqrtf(sv[11 + g]), MINN);
    float us = tan_k_((umxn / uxn) * ak_u, sq) / umxn;
    float u2 = us * us * sv[11 + g];
    float xy = wsc * us * sv[7 + g];
    float den = fmaxf(1.f - 2.f * kk * xy + kk * kk * w2 * u2, MINN);
    float a = (1.f - 2.f * kk * xy - kk * u2) / den;
    float b = (1.f + kk * w2) / den;
    float y2s = fmaxf(a * a * w2 + 2.f * a * b * xy + b * b * u2, 0.f);
    float yn = fmaxf(sqrtf(y2s), MINN);
    pscg[g] = artan_k_(yn, sq) / yn;
    cAg[g] = a * wsc;
    cBg[g] = b * us;
  }
  float gate[4][3];
#pragma unroll
  for (int g = 0; g < 4; ++g)
#pragma unroll
    for (int p = 0; p < 3; ++p)
      gate[g][p] = 1.f / (1.f + expf(-pscg[g] * (cAg[g] * gh[g][p] + cBg[g] * mx[g][p])));

  float s2v[2] = {0.f, 0.f};
#pragma unroll
  for (int p = 0; p < 3; ++p) {
    s2v[0] += th[p] * th[p];
    s2v[1] += th[p] * cc[p];
  }
  block_reduce_sum<2>(s2v, red);
  float un = fmaxf(sqrtf(s2v[0]), MINN);
  float esc = tan_k_(un, sq) / un;
  float cs1[3];
#pragma unroll
  for (int p = 0; p < 3; ++p) cs1[p] = esc * th[p];
  float d1 = esc * s2v[1];
  float s1sq = esc * esc * s2v[0];

  float tv = TS[r * SS + t];
  float xnt = fmaxf(sqrtf(768.f * tv * tv), MINN);
  float wxn_t = fmaxf(fabsf(tv) * sqrtf(s1sq), MINN);
  float s2s = tan_k_((wxn_t / xnt) * artan_k_(xnt, sq), sq) / wxn_t * tv;
  float s2sq = s2s * s2s * s1sq;

  float den_l = fmaxf(1.f + 2.f * kk * d1 + kk * kk * s1sq * c2, MINN);
  float al = (1.f + 2.f * kk * d1 - kk * c2) / den_l;
  float bl = (1.f + kk * s1sq) / den_l;
  float pcl = -al, qcl = bl;

  float xy2 = s2s * (pcl * s1sq + qcl * d1);
  float x2b = fmaxf(pcl * pcl * s1sq + 2.f * pcl * qcl * d1 + qcl * qcl * c2, 0.f);
  float y2b = s2sq;
  float den2 = fmaxf(1.f - 2.f * kk * xy2 + kk * kk * x2b * y2b, MINN);
  float a2 = (1.f - 2.f * kk * xy2 - kk * y2b) / den2;
  float b2 = (1.f + kk * x2b) / den2;
  float g1c = a2 * pcl + b2 * s2s;
  float g2c = a2 * qcl;
  float cadj[3];
#pragma unroll
  for (int p = 0; p < 3; ++p) cadj[p] = g1c * cs1[p] + g2c * cc[p];
  float adjsq = fmaxf(g1c * g1c * s1sq + 2.f * g1c * g2c * d1 + g2c * g2c * c2, 0.f);

  float wxi[3], wxf[3];
#pragma unroll
  for (int p = 0; p < 3; ++p) {
    wxi[p] = gate[1][p] * gate[3][p];
    wxf[p] = gate[0][p] * cadj[p];
  }
  float s3v[4] = {0.f, 0.f, 0.f, 0.f};
#pragma unroll
  for (int p = 0; p < 3; ++p) {
    s3v[0] += gate[3][p] * gate[3][p];
    s3v[1] += wxi[p] * wxi[p];
    s3v[2] += wxf[p] * wxf[p];
    s3v[3] += wxi[p] * wxf[p];
  }
  block_reduce_sum<4>(s3v, red);
  float xnct = fmaxf(sqrtf(s3v[0]), MINN);
  float wxni = fmaxf(sqrtf(s3v[1]), MINN);
  float psi = tan_k_((wxni / xnct) * artan_k_(xnct, sq), sq) / wxni;
  float pi2 = psi * psi * s3v[1];
  float xnadj = fmaxf(sqrtf(adjsq), MINN);
  float wxnf = fmaxf(sqrtf(s3v[2]), MINN);
  float psf = tan_k_((wxnf / xnadj) * artan_k_(xnadj, sq), sq) / wxnf;
  float pf2 = psf * psf * s3v[2];
  float xyp = psi * psf * s3v[3];
  float den3 = fmaxf(1.f - 2.f * kk * xyp + kk * kk * pi2 * pf2, MINN);
  float a3 = (1.f - 2.f * kk * xyp - kk * pf2) / den3;
  float b3 = (1.f + kk * pi2) / den3;
  float nc[3], tc[3];
#pragma unroll
  for (int p = 0; p < 3; ++p) {
    nc[p] = a3 * psi * wxi[p] + b3 * psf * wxf[p];
    tc[p] = tanhf(nc[p]);
  }
  float s4v[1] = {0.f};
#pragma unroll
  for (int p = 0; p < 3; ++p) s4v[0] += tc[p] * tc[p];
  block_reduce_sum<1>(s4v, red);
  float unh = fmaxf(sqrtf(s4v[0]), MINN);
  float ehs = tan_k_(unh, sq) / unh;
  float Esq = ehs * ehs * s4v[0];
  float En = fmaxf(sqrtf(Esq), MINN);
  float wxo[3];
#pragma unroll
  for (int p = 0; p < 3; ++p) wxo[p] = gate[2][p] * (ehs * tc[p]);
  float s5v[1] = {0.f};
#pragma unroll
  for (int p = 0; p < 3; ++p) s5v[0] += wxo[p] * wxo[p];
  block_reduce_sum<1>(s5v, red);
  float wxno = fmaxf(sqrtf(s5v[0]), MINN);
  float pso = tan_k_((wxno / En) * artan_k_(En, sq), sq) / wxno;

  size_t BSHc = (size_t)BB * SS * 768;
#pragma unroll
  for (int p = 0; p < 3; ++p) {
    int jj = tid + 256 * p;
    out[((size_t)r * SS + t) * 768 + jj] = gate[2][p];  // output = o gate
    float ncv = nc[p];
    float nhv = pso * wxo[p];
    ccR[r * 768 + jj] = ncv;
    hR[r * 768 + jj] = nhv;
    __hip_bfloat16 chh = __float2bfloat16(ncv);
    CH[r * 768 + jj] = chh;
    CL[r * 768 + jj] = __float2bfloat16(ncv - __bfloat162float(chh));
    __hip_bfloat16 hhh = __float2bfloat16(nhv);
    HH[r * 768 + jj] = hhh;
    HL[r * 768 + jj] = __float2bfloat16(nhv - __bfloat162float(hhh));
    if (t == SS - 1) {
      out[BSHc + (size_t)r * 768 + jj] = nhv;                    // h_last
      out[BSHc + (size_t)BB * 768 + (size_t)r * 768 + jj] = ncv; // c_last
    }
  }
}

extern "C" void kernel_launch(void* const* d_in, const int* in_sizes, int n_in,
                              void* d_out, int out_size, void* d_ws, size_t ws_size,
                              hipStream_t stream) {
  const float* inputs = (const float*)d_in[0];
  const float* ts = (const float*)d_in[1];
  const float* h0 = (const float*)d_in[2];
  const float* c0 = (const float*)d_in[3];
  const float* W_all = (const float*)d_in[4];
  const float* U_all = (const float*)d_in[5];
  const float* W_d = (const float*)d_in[6];
  const float* kptr = (const float*)d_in[7];
  float* ws = (float*)d_ws;
  float* out = (float*)d_out;

  // all offsets in float units
  size_t oCNT = 0;                     // 16 fl (64 B)
  size_t oCWH = 16;                    // 3840*768 bf16 = 1,474,560 fl
  size_t oCWL = oCWH + 1474560;
  size_t oCCR = oCWL + 1474560;        // fp32 state 49,152 fl each
  size_t oHR = oCCR + 49152;
  size_t oCH = oHR + 49152;            // bf16 state 24,576 fl each
  size_t oCL = oCH + 24576;
  size_t oHH = oCL + 24576;
  size_t oHL = oHH + 24576;
  size_t oGOUT = oHL + 24576;          // 245,760 fl
  size_t oXN = oGOUT + (size_t)BB * NCOL;
  size_t oUG = oXN + 8192;             // 12,582,912 fl
  size_t oXH = oUG + 12582912;         // 3,145,728 fl
  size_t oXL = oXH + 3145728;
  size_t oUH = oXL + 3145728;          // 1,179,648 fl
  size_t oUL = oUH + 1179648;

  unsigned int* cnt = (unsigned int*)(ws + oCNT);
  __hip_bfloat16* cwh = (__hip_bfloat16*)(ws + oCWH);
  __hip_bfloat16* cwl = (__hip_bfloat16*)(ws + oCWL);
  float* ccr = ws + oCCR;
  float* hr = ws + oHR;
  __hip_bfloat16* ch = (__hip_bfloat16*)(ws + oCH);
  __hip_bfloat16* cl = (__hip_bfloat16*)(ws + oCL);
  __hip_bfloat16* hh = (__hip_bfloat16*)(ws + oHH);
  __hip_bfloat16* hl = (__hip_bfloat16*)(ws + oHL);
  float* gout = ws + oGOUT;
  float* xn = ws + oXN;
  __hip_bfloat16* ug = (__hip_bfloat16*)(ws + oUG);
  __hip_bfloat16* xhh = (__hip_bfloat16*)(ws + oXH);
  __hip_bfloat16* xll = (__hip_bfloat16*)(ws + oXL);
  __hip_bfloat16* uhh = (__hip_bfloat16*)(ws + oUH);
  __hip_bfloat16* ull = (__hip_bfloat16*)(ws + oUL);

  hipMemsetAsync(cnt, 0, 64, stream);  // graph node: resets every replay
  k_build_cw<<<NCOL, 256, 0, stream>>>(W_all, W_d, cwh, cwl);
  k_init_state<<<BB, 256, 0, stream>>>(h0, c0, ccr, hr, ch, cl, hh, hl);
  k_split<<<(6291456 / 4 + 255) / 256, 256, 0, stream>>>(inputs, xhh, xll, 6291456 / 4);
  k_split<<<(2359296 / 4 + 255) / 256, 256, 0, stream>>>(U_all, uhh, ull, 2359296 / 4);
  k_gemm_xu_mfma<<<dim3(128, 48), 256, 0, stream>>>(xhh, xll, uhh, ull, ug);
  k_xnorm<<<BB * SS, 256, 0, stream>>>(inputs, xn);

  for (int t = 0; t < SS; ++t) {
    k_step<<<240, 256, 0, stream>>>(cwh, cwl, gout, cnt, ug, xn, ts, kptr, ccr, hr,
                                    ch, cl, hh, hl, out, t);
  }
}

// Round 11
// 4119.371 us; speedup vs baseline: 1.2336x; 1.2336x over previous
//
#include <hip/hip_runtime.h>
#include <hip/hip_bf16.h>
#include <math.h>

#define MINN 1e-7f

// Problem dims (fixed by setup_inputs)
#define BB 64
#define SS 128
#define NCOL 3840            // 768 (W_d) + 4*768 (gates)

typedef float f4 __attribute__((ext_vector_type(4)));
typedef short bf16x8 __attribute__((ext_vector_type(8)));
typedef float f32x4 __attribute__((ext_vector_type(4)));

__device__ __forceinline__ float artanh_c(float x) {
  x = fminf(fmaxf(x, -1.0f + 1e-6f), 1.0f - 1e-6f);
  return atanhf(x);
}
__device__ __forceinline__ float tan_k_(float x, float sq) { return tanhf(sq * x) / sq; }
__device__ __forceinline__ float artan_k_(float x, float sq) { return artanh_c(sq * x) / sq; }

// Block reduction over 256 threads (4 waves).
template <int N>
__device__ __forceinline__ void block_reduce_sum(float* v, float* red) {
#pragma unroll
  for (int m = 1; m < 64; m <<= 1) {
#pragma unroll
    for (int i = 0; i < N; ++i) v[i] += __shfl_xor(v[i], m, 64);
  }
  int wid = threadIdx.x >> 6;
  int lane = threadIdx.x & 63;
  if (lane == 0) {
#pragma unroll
    for (int i = 0; i < N; ++i) red[wid * N + i] = v[i];
  }
  __syncthreads();
#pragma unroll
  for (int i = 0; i < N; ++i) v[i] = red[i] + red[N + i] + red[2 * N + i] + red[3 * N + i];
  __syncthreads();
}

// Build combined weight matrix as bf16 hi/lo, [col][k] (k-contiguous = B-fragment ready).
__global__ __launch_bounds__(256) void k_build_cw(const float* __restrict__ W_all,
                                                  const float* __restrict__ W_d,
                                                  __hip_bfloat16* __restrict__ CWh,
                                                  __hip_bfloat16* __restrict__ CWl) {
  int col = blockIdx.x;  // 0..3839
#pragma unroll
  for (int p = 0; p < 3; ++p) {
    int k = threadIdx.x + 256 * p;
    float v;
    if (col < 768) {
      v = W_d[col * 768 + k];
    } else {
      int jm = col - 768;
      int g = jm / 768;
      int j2 = jm - g * 768;
      v = W_all[j2 * 3072 + g * 768 + k];
    }
    __hip_bfloat16 h = __float2bfloat16(v);
    CWh[(size_t)col * 768 + k] = h;
    CWl[(size_t)col * 768 + k] = __float2bfloat16(v - __bfloat162float(h));
  }
}

// Init: fp32 row-major state + bf16 hi/lo row-major copies (A-fragment ready).
__global__ __launch_bounds__(256) void k_init_state(
    const float* __restrict__ h0, const float* __restrict__ c0,
    float* __restrict__ ccR, float* __restrict__ hR,
    __hip_bfloat16* __restrict__ CH, __hip_bfloat16* __restrict__ CL,
    __hip_bfloat16* __restrict__ HH, __hip_bfloat16* __restrict__ HL) {
  int r = blockIdx.x;
#pragma unroll
  for (int p = 0; p < 3; ++p) {
    int j = threadIdx.x + 256 * p;
    float cv = c0[r * 768 + j];
    float hv = h0[r * 768 + j];
    ccR[r * 768 + j] = cv;
    hR[r * 768 + j] = hv;
    __hip_bfloat16 ch = __float2bfloat16(cv);
    CH[r * 768 + j] = ch;
    CL[r * 768 + j] = __float2bfloat16(cv - __bfloat162float(ch));
    __hip_bfloat16 hh = __float2bfloat16(hv);
    HH[r * 768 + j] = hh;
    HL[r * 768 + j] = __float2bfloat16(hv - __bfloat162float(hh));
  }
}

__global__ __launch_bounds__(256) void k_xnorm(const float* __restrict__ X,
                                               float* __restrict__ XN) {
  __shared__ float red[4];
  int r = blockIdx.x;
  float s = 0.f;
#pragma unroll
  for (int p = 0; p < 3; ++p) {
    float v = X[(size_t)r * 768 + threadIdx.x + 256 * p];
    s += v * v;
  }
#pragma unroll
  for (int m = 1; m < 64; m <<= 1) s += __shfl_xor(s, m, 64);
  if ((threadIdx.x & 63) == 0) red[threadIdx.x >> 6] = s;
  __syncthreads();
  if (threadIdx.x == 0) XN[r] = fmaxf(sqrtf(red[0] + red[1] + red[2] + red[3]), MINN);
}

// Split fp32 -> bf16 hi + bf16 lo (residual). Processes 4 elems/thread.
__global__ __launch_bounds__(256) void k_split(const float* __restrict__ src,
                                               __hip_bfloat16* __restrict__ hi,
                                               __hip_bfloat16* __restrict__ lo, int n4) {
  int i = blockIdx.x * 256 + threadIdx.x;
  if (i >= n4) return;
  f4 v = *(const f4*)(src + (size_t)i * 4);
#pragma unroll
  for (int j = 0; j < 4; ++j) {
    float x = (j == 0) ? v.x : (j == 1) ? v.y : (j == 2) ? v.z : v.w;
    __hip_bfloat16 h = __float2bfloat16(x);
    float r = x - __bfloat162float(h);
    hi[(size_t)i * 4 + j] = h;
    lo[(size_t)i * 4 + j] = __float2bfloat16(r);
  }
}

// MFMA U-path GEMM, 2-pass (xh*uh + xl*uh): OUT[i][m] = sum_k X[i][k]*U[m][k].
// 128x64 tile/WG: wave = 32 rows x 64 cols (loads:MFMA = 8:16 per k-iter).
__global__ __launch_bounds__(256) void k_gemm_xu_mfma(
    const __hip_bfloat16* __restrict__ Xh, const __hip_bfloat16* __restrict__ Xl,
    const __hip_bfloat16* __restrict__ Uh, __hip_bfloat16* __restrict__ OUT) {
  int tid = threadIdx.x;
  int wave = tid >> 6, lane = tid & 63;
  int r = lane & 15, kg = lane >> 4;
  int i0 = blockIdx.x * 128 + wave * 32;
  int m0 = blockIdx.y * 64;
  const __hip_bfloat16* xh0 = Xh + (size_t)(i0 + r) * 768 + kg * 8;
  const __hip_bfloat16* xh1 = Xh + (size_t)(i0 + 16 + r) * 768 + kg * 8;
  const __hip_bfloat16* xl0 = Xl + (size_t)(i0 + r) * 768 + kg * 8;
  const __hip_bfloat16* xl1 = Xl + (size_t)(i0 + 16 + r) * 768 + kg * 8;
  const __hip_bfloat16* uh = Uh + (size_t)(m0 + r) * 768 + kg * 8;
  f32x4 acc[2][4];
#pragma unroll
  for (int a = 0; a < 2; ++a)
#pragma unroll
    for (int b = 0; b < 4; ++b) acc[a][b] = {0.f, 0.f, 0.f, 0.f};
  for (int k0 = 0; k0 < 768; k0 += 32) {
    bf16x8 ah0 = *(const bf16x8*)(xh0 + k0);
    bf16x8 ah1 = *(const bf16x8*)(xh1 + k0);
    bf16x8 al0 = *(const bf16x8*)(xl0 + k0);
    bf16x8 al1 = *(const bf16x8*)(xl1 + k0);
    bf16x8 bh[4];
#pragma unroll
    for (int p = 0; p < 4; ++p) bh[p] = *(const bf16x8*)(uh + p * 12288 + k0);
#pragma unroll
    for (int p = 0; p < 4; ++p) {
      acc[0][p] = __builtin_amdgcn_mfma_f32_16x16x32_bf16(ah0, bh[p], acc[0][p], 0, 0, 0);
      acc[1][p] = __builtin_amdgcn_mfma_f32_16x16x32_bf16(ah1, bh[p], acc[1][p], 0, 0, 0);
      acc[0][p] = __builtin_amdgcn_mfma_f32_16x16x32_bf16(al0, bh[p], acc[0][p], 0, 0, 0);
      acc[1][p] = __builtin_amdgcn_mfma_f32_16x16x32_bf16(al1, bh[p], acc[1][p], 0, 0, 0);
    }
  }
  // C/D layout: col = m0+p*16+(lane&15), row = i0 + a*16 + kg*4 + jj
#pragma unroll
  for (int a = 0; a < 2; ++a)
#pragma unroll
    for (int p = 0; p < 4; ++p)
#pragma unroll
      for (int jj = 0; jj < 4; ++jj)
        OUT[(size_t)(i0 + a * 16 + kg * 4 + jj) * 3072 + m0 + p * 16 + r] =
            __float2bfloat16(acc[a][p][jj]);
}

// Per-step recurrent GEMM (3-pass hi/lo), traffic-optimal tiling r=64,c=64:
// grid(60,2): WG (cg,kh) computes GOUT2[kh][0..63][cg*64..+64] over k-half kh.
// Traffic: 120 WGs x 196KB = 23.6 MB/step (vs 59 MB at c=16).
__global__ __launch_bounds__(256) void k_step_gemm_mfma(
    const __hip_bfloat16* __restrict__ CWh, const __hip_bfloat16* __restrict__ CWl,
    const __hip_bfloat16* __restrict__ CH, const __hip_bfloat16* __restrict__ CL,
    const __hip_bfloat16* __restrict__ HH, const __hip_bfloat16* __restrict__ HL,
    float* __restrict__ GOUT2) {
  int cg = blockIdx.x;  // col-group 0..59 (64 cols each); cg<12 -> c-state
  int kh = blockIdx.y;  // k-half 0..1
  int wave = threadIdx.x >> 6, lane = threadIdx.x & 63;
  int r = lane & 15, kg = lane >> 4;
  int i0 = wave * 16;
  int m0 = cg * 64;
  int kb = kh * 384;
  const __hip_bfloat16* sh = (cg < 12 ? CH : HH) + (size_t)(i0 + r) * 768 + kb + kg * 8;
  const __hip_bfloat16* sl = (cg < 12 ? CL : HL) + (size_t)(i0 + r) * 768 + kb + kg * 8;
  const __hip_bfloat16* wh = CWh + (size_t)(m0 + r) * 768 + kb + kg * 8;
  const __hip_bfloat16* wl = CWl + (size_t)(m0 + r) * 768 + kb + kg * 8;
  f32x4 acc[4];
#pragma unroll
  for (int p = 0; p < 4; ++p) acc[p] = {0.f, 0.f, 0.f, 0.f};
#pragma unroll 4
  for (int k0 = 0; k0 < 384; k0 += 32) {
    bf16x8 ah = *(const bf16x8*)(sh + k0);
    bf16x8 al = *(const bf16x8*)(sl + k0);
#pragma unroll
    for (int p = 0; p < 4; ++p) {
      bf16x8 bh = *(const bf16x8*)(wh + p * 12288 + k0);
      bf16x8 bl = *(const bf16x8*)(wl + p * 12288 + k0);
      acc[p] = __builtin_amdgcn_mfma_f32_16x16x32_bf16(ah, bh, acc[p], 0, 0, 0);
      acc[p] = __builtin_amdgcn_mfma_f32_16x16x32_bf16(al, bh, acc[p], 0, 0, 0);
      acc[p] = __builtin_amdgcn_mfma_f32_16x16x32_bf16(ah, bl, acc[p], 0, 0, 0);
    }
  }
  float* gout = GOUT2 + (size_t)kh * (BB * NCOL);
#pragma unroll
  for (int p = 0; p < 4; ++p)
#pragma unroll
    for (int jj = 0; jj < 4; ++jj)
      gout[(size_t)(i0 + kg * 4 + jj) * NCOL + m0 + p * 16 + r] = acc[p][jj];
}

// Per-step pointwise hyperbolic math; one WG per batch row. 4 serial reductions.
__global__ __launch_bounds__(256) void k_step_pw(
    const float* __restrict__ GOUT2, const __hip_bfloat16* __restrict__ UG,
    const float* __restrict__ XN, const float* __restrict__ TS,
    const float* __restrict__ kptr, float* __restrict__ ccR, float* __restrict__ hR,
    __hip_bfloat16* __restrict__ CH, __hip_bfloat16* __restrict__ CL,
    __hip_bfloat16* __restrict__ HH, __hip_bfloat16* __restrict__ HL,
    float* __restrict__ out, int t) {
  __shared__ float red[64];
  int r = blockIdx.x;
  int tid = threadIdx.x;
  float kk = kptr[0];
  float sq = sqrtf(-kk);
  const float* grow0 = GOUT2 + (size_t)r * NCOL;
  const float* grow1 = GOUT2 + (size_t)BB * NCOL + (size_t)r * NCOL;
  int i = r * SS + t;
  const __hip_bfloat16* urow = UG + (size_t)i * 3072;

  float cc[3], h[3], mv[3], gh[4][3], mx[4][3];
#pragma unroll
  for (int p = 0; p < 3; ++p) {
    int j = tid + 256 * p;
    cc[p] = ccR[r * 768 + j];
    h[p] = hR[r * 768 + j];
    mv[p] = grow0[j] + grow1[j];
#pragma unroll
    for (int g = 0; g < 4; ++g) {
      gh[g][p] = grow0[768 + g * 768 + j] + grow1[768 + g * 768 + j];
      mx[g][p] = __bfloat162float(urow[g * 768 + j]);
    }
  }

  float sv[15];
#pragma unroll
  for (int q = 0; q < 15; ++q) sv[q] = 0.f;
#pragma unroll
  for (int p = 0; p < 3; ++p) {
    sv[0] += cc[p] * cc[p];
    sv[1] += h[p] * h[p];
    sv[2] += mv[p] * mv[p];
#pragma unroll
    for (int g = 0; g < 4; ++g) {
      sv[3 + g] += gh[g][p] * gh[g][p];
      sv[7 + g] += gh[g][p] * mx[g][p];
      sv[11 + g] += mx[g][p] * mx[g][p];
    }
  }
  block_reduce_sum<15>(sv, red);
  float c2 = sv[0], h2 = sv[1], mvn2 = sv[2];
  float xn_c = fmaxf(sqrtf(c2), MINN);
  float xn_h = fmaxf(sqrtf(h2), MINN);
  float mxn_d = fmaxf(sqrtf(mvn2), MINN);

  float r_d = (mxn_d / xn_c) * artan_k_(xn_c, sq);
  float twd = tan_k_(r_d, sq);
  float wdsc = twd / mxn_d;
  float yn_d = fmaxf(fabsf(twd), MINN);
  float lsc = (artan_k_(yn_d, sq) / yn_d) * wdsc;
  float th[3];
#pragma unroll
  for (int p = 0; p < 3; ++p) th[p] = tanhf(lsc * mv[p]);

  float uxn = XN[i];
  float ak_h = artan_k_(xn_h, sq);
  float ak_u = artan_k_(uxn, sq);
  float cAg[4], cBg[4], pscg[4];
#pragma unroll
  for (int g = 0; g < 4; ++g) {
    float ghn = fmaxf(sqrtf(sv[3 + g]), MINN);
    float tg = tan_k_((ghn / xn_h) * ak_h, sq);
    float wsc = tg / ghn;
    float w2 = tg * tg;
    float umxn = fmaxf(sqrtf(sv[11 + g]), MINN);
    float us = tan_k_((umxn / uxn) * ak_u, sq) / umxn;
    float u2 = us * us * sv[11 + g];
    float xy = wsc * us * sv[7 + g];
    float den = fmaxf(1.f - 2.f * kk * xy + kk * kk * w2 * u2, MINN);
    float a = (1.f - 2.f * kk * xy - kk * u2) / den;
    float b = (1.f + kk * w2) / den;
    float y2s = fmaxf(a * a * w2 + 2.f * a * b * xy + b * b * u2, 0.f);
    float yn = fmaxf(sqrtf(y2s), MINN);
    pscg[g] = artan_k_(yn, sq) / yn;
    cAg[g] = a * wsc;
    cBg[g] = b * us;
  }
  float gate[4][3];
#pragma unroll
  for (int g = 0; g < 4; ++g)
#pragma unroll
    for (int p = 0; p < 3; ++p)
      gate[g][p] = 1.f / (1.f + expf(-pscg[g] * (cAg[g] * gh[g][p] + cBg[g] * mx[g][p])));

  float s2v[2] = {0.f, 0.f};
#pragma unroll
  for (int p = 0; p < 3; ++p) {
    s2v[0] += th[p] * th[p];
    s2v[1] += th[p] * cc[p];
  }
  block_reduce_sum<2>(s2v, red);
  float un = fmaxf(sqrtf(s2v[0]), MINN);
  float esc = tan_k_(un, sq) / un;
  float cs1[3];
#pragma unroll
  for (int p = 0; p < 3; ++p) cs1[p] = esc * th[p];
  float d1 = esc * s2v[1];
  float s1sq = esc * esc * s2v[0];

  float tv = TS[r * SS + t];
  float xnt = fmaxf(sqrtf(768.f * tv * tv), MINN);
  float wxn_t = fmaxf(fabsf(tv) * sqrtf(s1sq), MINN);
  float s2s = tan_k_((wxn_t / xnt) * artan_k_(xnt, sq), sq) / wxn_t * tv;
  float s2sq = s2s * s2s * s1sq;

  float den_l = fmaxf(1.f + 2.f * kk * d1 + kk * kk * s1sq * c2, MINN);
  float al = (1.f + 2.f * kk * d1 - kk * c2) / den_l;
  float bl = (1.f + kk * s1sq) / den_l;
  float pcl = -al, qcl = bl;

  float xy2 = s2s * (pcl * s1sq + qcl * d1);
  float x2b = fmaxf(pcl * pcl * s1sq + 2.f * pcl * qcl * d1 + qcl * qcl * c2, 0.f);
  float y2b = s2sq;
  float den2 = fmaxf(1.f - 2.f * kk * xy2 + kk * kk * x2b * y2b, MINN);
  float a2 = (1.f - 2.f * kk * xy2 - kk * y2b) / den2;
  float b2 = (1.f + kk * x2b) / den2;
  float g1c = a2 * pcl + b2 * s2s;
  float g2c = a2 * qcl;
  float cadj[3];
#pragma unroll
  for (int p = 0; p < 3; ++p) cadj[p] = g1c * cs1[p] + g2c * cc[p];
  float adjsq = fmaxf(g1c * g1c * s1sq + 2.f * g1c * g2c * d1 + g2c * g2c * c2, 0.f);

  float wxi[3], wxf[3];
#pragma unroll
  for (int p = 0; p < 3; ++p) {
    wxi[p] = gate[1][p] * gate[3][p];
    wxf[p] = gate[0][p] * cadj[p];
  }
  float s3v[4] = {0.f, 0.f, 0.f, 0.f};
#pragma unroll
  for (int p = 0; p < 3; ++p) {
    s3v[0] += gate[3][p] * gate[3][p];
    s3v[1] += wxi[p] * wxi[p];
    s3v[2] += wxf[p] * wxf[p];
    s3v[3] += wxi[p] * wxf[p];
  }
  block_reduce_sum<4>(s3v, red);
  float xnct = fmaxf(sqrtf(s3v[0]), MINN);
  float wxni = fmaxf(sqrtf(s3v[1]), MINN);
  float psi = tan_k_((wxni / xnct) * artan_k_(xnct, sq), sq) / wxni;
  float pi2 = psi * psi * s3v[1];
  float xnadj = fmaxf(sqrtf(adjsq), MINN);
  float wxnf = fmaxf(sqrtf(s3v[2]), MINN);
  float psf = tan_k_((wxnf / xnadj) * artan_k_(xnadj, sq), sq) / wxnf;
  float pf2 = psf * psf * s3v[2];
  float xyp = psi * psf * s3v[3];
  float den3 = fmaxf(1.f - 2.f * kk * xyp + kk * kk * pi2 * pf2, MINN);
  float a3 = (1.f - 2.f * kk * xyp - kk * pf2) / den3;
  float b3 = (1.f + kk * pi2) / den3;
  float nc[3], tc[3];
#pragma unroll
  for (int p = 0; p < 3; ++p) {
    nc[p] = a3 * psi * wxi[p] + b3 * psf * wxf[p];
    tc[p] = tanhf(nc[p]);
  }
  // merged reduction: {|tc|^2, sum gate2^2*tc^2}
  float s4v[2] = {0.f, 0.f};
#pragma unroll
  for (int p = 0; p < 3; ++p) {
    s4v[0] += tc[p] * tc[p];
    float gt = gate[2][p] * tc[p];
    s4v[1] += gt * gt;
  }
  block_reduce_sum<2>(s4v, red);
  float unh = fmaxf(sqrtf(s4v[0]), MINN);
  float ehs = tan_k_(unh, sq) / unh;
  float Esq = ehs * ehs * s4v[0];
  float En = fmaxf(sqrtf(Esq), MINN);
  float wxno = fmaxf(ehs * sqrtf(s4v[1]), MINN);
  float pso = tan_k_((wxno / En) * artan_k_(En, sq), sq) / wxno;

  size_t BSHc = (size_t)BB * SS * 768;
#pragma unroll
  for (int p = 0; p < 3; ++p) {
    int j = tid + 256 * p;
    out[((size_t)r * SS + t) * 768 + j] = gate[2][p];  // output = o gate
    float ncv = nc[p];
    float nhv = pso * (gate[2][p] * (ehs * tc[p]));
    ccR[r * 768 + j] = ncv;
    hR[r * 768 + j] = nhv;
    __hip_bfloat16 chh = __float2bfloat16(ncv);
    CH[r * 768 + j] = chh;
    CL[r * 768 + j] = __float2bfloat16(ncv - __bfloat162float(chh));
    __hip_bfloat16 hhh = __float2bfloat16(nhv);
    HH[r * 768 + j] = hhh;
    HL[r * 768 + j] = __float2bfloat16(nhv - __bfloat162float(hhh));
    if (t == SS - 1) {
      out[BSHc + (size_t)r * 768 + j] = nhv;                    // h_last
      out[BSHc + (size_t)BB * 768 + (size_t)r * 768 + j] = ncv; // c_last
    }
  }
}

extern "C" void kernel_launch(void* const* d_in, const int* in_sizes, int n_in,
                              void* d_out, int out_size, void* d_ws, size_t ws_size,
                              hipStream_t stream) {
  const float* inputs = (const float*)d_in[0];
  const float* ts = (const float*)d_in[1];
  const float* h0 = (const float*)d_in[2];
  const float* c0 = (const float*)d_in[3];
  const float* W_all = (const float*)d_in[4];
  const float* U_all = (const float*)d_in[5];
  const float* W_d = (const float*)d_in[6];
  const float* kptr = (const float*)d_in[7];
  float* ws = (float*)d_ws;
  float* out = (float*)d_out;

  // all offsets in float units
  size_t oCWH = 0;                     // 3840*768 bf16 = 1,474,560 fl
  size_t oCWL = oCWH + 1474560;
  size_t oCCR = oCWL + 1474560;        // fp32 state 49,152 fl each
  size_t oHR = oCCR + 49152;
  size_t oCH = oHR + 49152;            // bf16 state 24,576 fl each
  size_t oCL = oCH + 24576;
  size_t oHH = oCL + 24576;
  size_t oHL = oHH + 24576;
  size_t oGOUT = oHL + 24576;          // 2 x 245,760 fl (k-partials)
  size_t oXN = oGOUT + 2 * (size_t)BB * NCOL;
  size_t oUG = oXN + 8192;             // 12,582,912 fl
  size_t oXH = oUG + 12582912;         // 3,145,728 fl
  size_t oXL = oXH + 3145728;
  size_t oUH = oXL + 3145728;          // 1,179,648 fl
  size_t oUL = oUH + 1179648;

  __hip_bfloat16* cwh = (__hip_bfloat16*)(ws + oCWH);
  __hip_bfloat16* cwl = (__hip_bfloat16*)(ws + oCWL);
  float* ccr = ws + oCCR;
  float* hr = ws + oHR;
  __hip_bfloat16* ch = (__hip_bfloat16*)(ws + oCH);
  __hip_bfloat16* cl = (__hip_bfloat16*)(ws + oCL);
  __hip_bfloat16* hh = (__hip_bfloat16*)(ws + oHH);
  __hip_bfloat16* hl = (__hip_bfloat16*)(ws + oHL);
  float* gout = ws + oGOUT;
  float* xn = ws + oXN;
  __hip_bfloat16* ug = (__hip_bfloat16*)(ws + oUG);
  __hip_bfloat16* xhh = (__hip_bfloat16*)(ws + oXH);
  __hip_bfloat16* xll = (__hip_bfloat16*)(ws + oXL);
  __hip_bfloat16* uhh = (__hip_bfloat16*)(ws + oUH);
  __hip_bfloat16* ull = (__hip_bfloat16*)(ws + oUL);

  k_build_cw<<<NCOL, 256, 0, stream>>>(W_all, W_d, cwh, cwl);
  k_init_state<<<BB, 256, 0, stream>>>(h0, c0, ccr, hr, ch, cl, hh, hl);
  k_split<<<(6291456 / 4 + 255) / 256, 256, 0, stream>>>(inputs, xhh, xll, 6291456 / 4);
  k_split<<<(2359296 / 4 + 255) / 256, 256, 0, stream>>>(U_all, uhh, ull, 2359296 / 4);
  k_gemm_xu_mfma<<<dim3(64, 48), 256, 0, stream>>>(xhh, xll, uhh, ug);
  k_xnorm<<<BB * SS, 256, 0, stream>>>(inputs, xn);

  for (int t = 0; t < SS; ++t) {
    k_step_gemm_mfma<<<dim3(60, 2), 256, 0, stream>>>(cwh, cwl, ch, cl, hh, hl, gout);
    k_step_pw<<<BB, 256, 0, stream>>>(gout, ug, xn, ts, kptr, ccr, hr, ch, cl, hh, hl,
                                      out, t);
  }
}